// Round 2
// baseline (263.713 us; speedup 1.0000x reference)
//
#include <hip/hip_runtime.h>
#include <math.h>

#define NS 1000
#define NV 200
#define NF 5
#define NK 80
#define EPSF 1e-5f

// fp32(2*pi); reference wraps with jnp.mod(x, 2pi) in f32.
#define TWOPI_F 6.28318530717958647692f
// fp32(2*pi/16) -- the scan multiplies fp32(j) by this constant.
#define STEP_F  0.39269908169872414f

static __device__ __forceinline__ float frcp(float v) {
    return __builtin_amdgcn_rcpf(v);
}

// One block per sample. 512 threads (8 waves) for latency hiding.
//   Phase 1: per-vertex tables -> LDS (12 floats per vertex).
//   Phase 2: thread = (q, j, tp): q = tid>>7 = vertex quarter (50 v each),
//            j = rotation, tp = theta-pair. 50 fp32 accumulators per thread.
//   Phase 3: zero desc LDS, combine quarter-partials via ds_add_f32 atomics.
//   Phase 4: thread = (f, jout), 400 active: cf = desc . W col, max over 16
//            rotations, +b, relu, store out[s][jout][f].
__global__ __launch_bounds__(512) void lsres_fused(
        const float* __restrict__ x,
        const float* __restrict__ mu_rho,
        const float* __restrict__ sigma_rho,
        const float* __restrict__ mu_theta,
        const float* __restrict__ sigma_theta,
        const float* __restrict__ Wc,
        const float* __restrict__ bc,
        float* __restrict__ out) {
    // 1600 float4 = 25.6 KB. First 600 float4 (= NV*3) hold the phase-1/2
    // vertex tables; after phase 2 the array is reused for desc[16][5][80].
    __shared__ float4 smem4[1600];
    float* smem = (float*)smem4;

    const int s     = blockIdx.x;
    const int tid   = threadIdx.x;
    const int l128  = tid & 127;
    const int q     = tid >> 7;      // vertex quarter 0..3
    const int j     = l128 >> 3;     // rotation 0..15
    const int tp    = l128 & 7;      // theta-pair 0..7
    const int t0    = tp * 2;        // theta bins t0, t0+1

    // --- per-thread constants (theta-bin Gaussians; F rows are identical) ---
    const float mu0 = mu_theta[t0];
    const float mu1 = mu_theta[t0 + 1];
    const float sg0 = sigma_theta[t0];
    const float sg1 = sigma_theta[t0 + 1];
    const float ist0 = 1.0f / (sg0 * sg0 + EPSF);
    const float ist1 = 1.0f / (sg1 * sg1 + EPSF);
    const float joff = (float)j * STEP_F;

    float mr[5], isr[5];
#pragma unroll
    for (int r = 0; r < 5; ++r) {
        mr[r] = mu_rho[r * 16];           // mu_rho[k] depends only on r = k/16
        float sr = sigma_rho[r * 16];
        isr[r] = 1.0f / (sr * sr + EPSF);
    }

    // --- Phase 1: vertex tables ---
    for (int v = tid; v < NV; v += 512) {
        const float* xe = x + ((size_t)s * NV + v) * 8;
        float4 x0 = *(const float4*)(xe);       // feat0..3
        float4 x1 = *(const float4*)(xe + 4);   // feat4, rho, theta, mask
        float rho = x1.y, theta = x1.z, mask = x1.w;
        float rg[5];
        float srg = 0.0f;
#pragma unroll
        for (int r = 0; r < 5; ++r) {
            float d = rho - mr[r];
            rg[r] = __expf(-d * d * isr[r]);
            srg += rg[r];
        }
        // act_norm = mask*Rg*T / (mask*sumRg*sumT + eps); fold mask into feat
        // and into the denominator term.
        smem4[v * 3 + 0] = make_float4(x0.x * mask, x0.y * mask, x0.z * mask, x0.w * mask);
        smem4[v * 3 + 1] = make_float4(x1.x * mask, rg[0], rg[1], rg[2]);
        smem4[v * 3 + 2] = make_float4(rg[3], rg[4], mask * srg, theta);
    }
    __syncthreads();

    // --- Phase 2: accumulate desc partials over this quarter's vertices ---
    float acc[5][5][2];
#pragma unroll
    for (int f = 0; f < 5; ++f)
#pragma unroll
        for (int r = 0; r < 5; ++r) {
            acc[f][r][0] = 0.0f;
            acc[f][r][1] = 0.0f;
        }

    const int vbase = q * (NV / 4);
#pragma unroll 2
    for (int vi = 0; vi < NV / 4; ++vi) {
        const int v = vbase + vi;
        float4 a  = smem4[v * 3 + 0];   // fm0..3
        float4 bv = smem4[v * 3 + 1];   // fm4, rg0..2
        float4 c  = smem4[v * 3 + 2];   // rg3, rg4, mask*sumRg, theta

        // th = mod(theta + j*step, 2pi) with the reference's f32 wrap decision.
        float th = c.w + joff;
        th = (th >= TWOPI_F) ? (th - TWOPI_F) : th;

        float d0 = th - mu0;
        float d1 = th - mu1;
        float T0 = __expf(-d0 * d0 * ist0);
        float T1 = __expf(-d1 * d1 * ist1);

        // sum of T over the 16 theta bins of rotation j (8-lane group, 2 bins each)
        float sT = T0 + T1;
        sT += __shfl_xor(sT, 1);
        sT += __shfl_xor(sT, 2);
        sT += __shfl_xor(sT, 4);

        float inv = frcp(fmaf(c.z, sT, EPSF));
        float p0 = T0 * inv;
        float p1 = T1 * inv;

        float fm[5] = {a.x, a.y, a.z, a.w, bv.x};
        float rg[5] = {bv.y, bv.z, bv.w, c.x, c.y};
#pragma unroll
        for (int r = 0; r < 5; ++r) {
            float g0 = rg[r] * p0;
            float g1 = rg[r] * p1;
#pragma unroll
            for (int f = 0; f < 5; ++f) {
                acc[f][r][0] = fmaf(fm[f], g0, acc[f][r][0]);
                acc[f][r][1] = fmaf(fm[f], g1, acc[f][r][1]);
            }
        }
    }
    __syncthreads();   // all quarters done reading the vertex tables

    // --- Phase 3: desc[j][f][k] in LDS, combine quarters via ds_add_f32 ---
    for (int i = tid; i < 16 * NF * NK; i += 512) smem[i] = 0.0f;
    __syncthreads();
#pragma unroll
    for (int f = 0; f < 5; ++f)
#pragma unroll
        for (int r = 0; r < 5; ++r) {
            int idx = (j * 5 + f) * NK + r * 16 + t0;
            atomicAdd(&smem[idx],     acc[f][r][0]);
            atomicAdd(&smem[idx + 1], acc[f][r][1]);
        }
    __syncthreads();

    // --- Phase 4: cf = desc . W, max over rotations, +b, relu ---
    if (tid < NF * NK) {
        const int f  = tid / NK;     // feature
        const int jo = tid % NK;     // output bin (consecutive lanes -> coalesced W)

        float a2[16];
#pragma unroll
        for (int jj = 0; jj < 16; ++jj) a2[jj] = 0.0f;

        const float* Wf = Wc + f * (NK * NK) + jo;
        for (int k4 = 0; k4 < 20; ++k4) {
            const float* wp = Wf + (k4 * 4) * NK;
            float w0 = wp[0];
            float w1 = wp[NK];
            float w2 = wp[2 * NK];
            float w3 = wp[3 * NK];
#pragma unroll
            for (int jj = 0; jj < 16; ++jj) {
                float4 d4 = smem4[(jj * 5 + f) * 20 + k4];   // wave-broadcast
                a2[jj] = fmaf(d4.x, w0, a2[jj]);
                a2[jj] = fmaf(d4.y, w1, a2[jj]);
                a2[jj] = fmaf(d4.z, w2, a2[jj]);
                a2[jj] = fmaf(d4.w, w3, a2[jj]);
            }
        }

        float m = -INFINITY;
#pragma unroll
        for (int jj = 0; jj < 16; ++jj) m = fmaxf(m, a2[jj]);

        float val = fmaxf(m + bc[f * NK + jo], 0.0f);
        out[(size_t)s * (NK * NF) + jo * NF + f] = val;   // out[s][jout][f]
    }
}

extern "C" void kernel_launch(void* const* d_in, const int* in_sizes, int n_in,
                              void* d_out, int out_size, void* d_ws, size_t ws_size,
                              hipStream_t stream) {
    const float* x           = (const float*)d_in[0];
    const float* mu_rho      = (const float*)d_in[1];
    const float* sigma_rho   = (const float*)d_in[2];
    const float* mu_theta    = (const float*)d_in[3];
    const float* sigma_theta = (const float*)d_in[4];
    const float* Wc          = (const float*)d_in[5];
    const float* bc          = (const float*)d_in[6];
    float* out = (float*)d_out;

    lsres_fused<<<dim3(NS), dim3(512), 0, stream>>>(
        x, mu_rho, sigma_rho, mu_theta, sigma_theta, Wc, bc, out);
}

// Round 3
// 256.360 us; speedup vs baseline: 1.0287x; 1.0287x over previous
//
#include <hip/hip_runtime.h>
#include <math.h>

#define NS 1000
#define NV 200
#define NF 5
#define NK 80
#define EPSF 1e-5f

// fp32(2*pi); reference wraps with jnp.mod(x, 2pi) in f32.
#define TWOPI_F 6.28318530717958647692f
// fp32(2*pi/16) -- the scan multiplies fp32(j) by this constant.
#define STEP_F  0.39269908169872414f

static __device__ __forceinline__ float frcp(float v) {
    return __builtin_amdgcn_rcpf(v);
}

// 2 blocks per sample (rotation halves), 256 threads (4 waves).
//   thread = (q, jl, tp): q = tid>>6 vertex quarter (50 v), jl = (tid>>3)&7
//   local rotation (global j = jhalf*8+jl), tp = tid&7 theta-pair.
// Phase 1: per-vertex tables -> LDS (12 floats per vertex).
// Phase 2: accumulate desc quarter-partials, 50 fp32 regs per thread.
//          NOTE: needs ~85 VGPRs live; __launch_bounds__(256,4) caps at 128.
//          Do NOT raise min-waves: at 512 thr the compiler capped VGPR=48 and
//          spilled the accumulators (R2: 218 us vs 91 us).
// Phase 3: zero desc LDS, merge quarters via ds_add_f32.
// Phase 4: thread = (f, jo-pair), 200 active: cf = desc . W, max over the
//          8 local rotations, +b, relu, merge halves via int atomicMax on out
//          (post-relu values >= 0, int order == float order; 0xAA poison and
//          memset-0 are both below any valid value as signed int).
__global__ __launch_bounds__(256, 4) void lsres_fused(
        const float* __restrict__ x,
        const float* __restrict__ mu_rho,
        const float* __restrict__ sigma_rho,
        const float* __restrict__ mu_theta,
        const float* __restrict__ sigma_theta,
        const float* __restrict__ Wc,
        const float* __restrict__ bc,
        float* __restrict__ out) {
    // 3200 floats = 12.8 KB: phase 1/2 vertex tables use the first 2400
    // (600 float4); after phase 2 reused as desc[8][5][80] (3200 floats).
    __shared__ float smem[3200];
    float4* smem4 = (float4*)smem;

    const int bid   = blockIdx.x;
    const int s     = bid >> 1;
    const int jhalf = bid & 1;
    const int tid   = threadIdx.x;
    const int q     = tid >> 6;        // vertex quarter 0..3 (= wave id)
    const int jl    = (tid >> 3) & 7;  // local rotation 0..7
    const int tp    = tid & 7;         // theta-pair 0..7
    const int t0    = tp * 2;          // theta bins t0, t0+1
    const int jg    = jhalf * 8 + jl;  // global rotation 0..15

    // --- per-thread constants (theta-bin Gaussians; F rows are identical) ---
    const float mu0 = mu_theta[t0];
    const float mu1 = mu_theta[t0 + 1];
    const float sg0 = sigma_theta[t0];
    const float sg1 = sigma_theta[t0 + 1];
    const float ist0 = 1.0f / (sg0 * sg0 + EPSF);
    const float ist1 = 1.0f / (sg1 * sg1 + EPSF);
    const float joff = (float)jg * STEP_F;

    float mr[5], isr[5];
#pragma unroll
    for (int r = 0; r < 5; ++r) {
        mr[r] = mu_rho[r * 16];           // mu_rho[k] depends only on r = k/16
        float sr = sigma_rho[r * 16];
        isr[r] = 1.0f / (sr * sr + EPSF);
    }

    // --- Phase 1: vertex tables ---
    if (tid < NV) {
        const int v = tid;
        const float* xe = x + ((size_t)s * NV + v) * 8;
        float4 x0 = *(const float4*)(xe);       // feat0..3
        float4 x1 = *(const float4*)(xe + 4);   // feat4, rho, theta, mask
        float rho = x1.y, theta = x1.z, mask = x1.w;
        float rg[5];
        float srg = 0.0f;
#pragma unroll
        for (int r = 0; r < 5; ++r) {
            float d = rho - mr[r];
            rg[r] = __expf(-d * d * isr[r]);
            srg += rg[r];
        }
        // act_norm = mask*Rg*T / (mask*sumRg*sumT + eps); fold mask into feat
        // and into the denominator term.
        smem4[v * 3 + 0] = make_float4(x0.x * mask, x0.y * mask, x0.z * mask, x0.w * mask);
        smem4[v * 3 + 1] = make_float4(x1.x * mask, rg[0], rg[1], rg[2]);
        smem4[v * 3 + 2] = make_float4(rg[3], rg[4], mask * srg, theta);
    }
    __syncthreads();

    // --- Phase 2: accumulate desc partials over this quarter's vertices ---
    float acc[5][5][2];
#pragma unroll
    for (int f = 0; f < 5; ++f)
#pragma unroll
        for (int r = 0; r < 5; ++r) {
            acc[f][r][0] = 0.0f;
            acc[f][r][1] = 0.0f;
        }

    const int vbase = q * (NV / 4);
    for (int vi = 0; vi < NV / 4; ++vi) {
        const int v = vbase + vi;
        float4 a  = smem4[v * 3 + 0];   // fm0..3       (wave-broadcast reads)
        float4 bv = smem4[v * 3 + 1];   // fm4, rg0..2
        float4 c  = smem4[v * 3 + 2];   // rg3, rg4, mask*sumRg, theta

        // th = mod(theta + j*step, 2pi); theta < 2pi, joff < 2pi, so one
        // conditional subtract reproduces the reference's f32 wrap decision.
        float th = c.w + joff;
        th = (th >= TWOPI_F) ? (th - TWOPI_F) : th;

        float d0 = th - mu0;
        float d1 = th - mu1;
        float T0 = __expf(-d0 * d0 * ist0);
        float T1 = __expf(-d1 * d1 * ist1);

        // sum of T over the 16 theta bins of rotation jg
        // (8-lane tp-group, 2 bins each; xor 1/2/4 stays inside the group)
        float sT = T0 + T1;
        sT += __shfl_xor(sT, 1);
        sT += __shfl_xor(sT, 2);
        sT += __shfl_xor(sT, 4);

        float inv = frcp(fmaf(c.z, sT, EPSF));
        float p0 = T0 * inv;
        float p1 = T1 * inv;

        float fm[5] = {a.x, a.y, a.z, a.w, bv.x};
        float rg[5] = {bv.y, bv.z, bv.w, c.x, c.y};
#pragma unroll
        for (int r = 0; r < 5; ++r) {
            float g0 = rg[r] * p0;
            float g1 = rg[r] * p1;
#pragma unroll
            for (int f = 0; f < 5; ++f) {
                acc[f][r][0] = fmaf(fm[f], g0, acc[f][r][0]);
                acc[f][r][1] = fmaf(fm[f], g1, acc[f][r][1]);
            }
        }
    }
    __syncthreads();   // all quarters done reading the vertex tables

    // --- Phase 3: desc[jl][f][k] in LDS, merge quarters via ds_add_f32 ---
    for (int i = tid; i < 8 * NF * NK; i += 256) smem[i] = 0.0f;
    __syncthreads();
#pragma unroll
    for (int f = 0; f < 5; ++f)
#pragma unroll
        for (int r = 0; r < 5; ++r) {
            int idx = (jl * 5 + f) * NK + r * 16 + t0;
            atomicAdd(&smem[idx],     acc[f][r][0]);
            atomicAdd(&smem[idx + 1], acc[f][r][1]);
        }
    __syncthreads();

    // --- Phase 4: cf = desc . W for this half's 8 rotations, max, merge ---
    if (tid < 200) {
        const int f  = tid / 40;            // feature
        const int jo = (tid % 40) * 2;      // output bins jo, jo+1 (coalesced W)

        float a2[8][2];
#pragma unroll
        for (int jj = 0; jj < 8; ++jj) { a2[jj][0] = 0.0f; a2[jj][1] = 0.0f; }

        const float* Wf = Wc + f * (NK * NK) + jo;
        for (int k4 = 0; k4 < 20; ++k4) {
            const float* wp = Wf + (k4 * 4) * NK;
            float2 w0 = *(const float2*)(wp);
            float2 w1 = *(const float2*)(wp + NK);
            float2 w2 = *(const float2*)(wp + 2 * NK);
            float2 w3 = *(const float2*)(wp + 3 * NK);
#pragma unroll
            for (int jj = 0; jj < 8; ++jj) {
                float4 d4 = smem4[(jj * 5 + f) * 20 + k4];   // wave-broadcast
                a2[jj][0] = fmaf(d4.x, w0.x, a2[jj][0]);
                a2[jj][0] = fmaf(d4.y, w1.x, a2[jj][0]);
                a2[jj][0] = fmaf(d4.z, w2.x, a2[jj][0]);
                a2[jj][0] = fmaf(d4.w, w3.x, a2[jj][0]);
                a2[jj][1] = fmaf(d4.x, w0.y, a2[jj][1]);
                a2[jj][1] = fmaf(d4.y, w1.y, a2[jj][1]);
                a2[jj][1] = fmaf(d4.z, w2.y, a2[jj][1]);
                a2[jj][1] = fmaf(d4.w, w3.y, a2[jj][1]);
            }
        }

        float m0 = -INFINITY, m1 = -INFINITY;
#pragma unroll
        for (int jj = 0; jj < 8; ++jj) {
            m0 = fmaxf(m0, a2[jj][0]);
            m1 = fmaxf(m1, a2[jj][1]);
        }

        float v0 = fmaxf(m0 + bc[f * NK + jo],     0.0f);
        float v1 = fmaxf(m1 + bc[f * NK + jo + 1], 0.0f);
        // out[s][jout][f]; halves merged with int atomicMax (vals >= 0).
        int* ob = (int*)(out + (size_t)s * (NK * NF));
        atomicMax(&ob[jo * NF + f],       __float_as_int(v0));
        atomicMax(&ob[(jo + 1) * NF + f], __float_as_int(v1));
    }
}

extern "C" void kernel_launch(void* const* d_in, const int* in_sizes, int n_in,
                              void* d_out, int out_size, void* d_ws, size_t ws_size,
                              hipStream_t stream) {
    const float* x           = (const float*)d_in[0];
    const float* mu_rho      = (const float*)d_in[1];
    const float* sigma_rho   = (const float*)d_in[2];
    const float* mu_theta    = (const float*)d_in[3];
    const float* sigma_theta = (const float*)d_in[4];
    const float* Wc          = (const float*)d_in[5];
    const float* bc          = (const float*)d_in[6];
    float* out = (float*)d_out;

    lsres_fused<<<dim3(NS * 2), dim3(256), 0, stream>>>(
        x, mu_rho, sigma_rho, mu_theta, sigma_theta, Wc, bc, out);
}